// Round 5
// baseline (465.662 us; speedup 1.0000x reference)
//
#include <hip/hip_runtime.h>
#include <math.h>

#define BB 32
#define LL 2048
#define DD 1024
#define HH 16
#define DHH 64
#define NCK 32         // chunks per batch
#define CH  64         // rows per chunk
#define NG  (CH / 4)   // 4-row groups per chunk

#if defined(__has_builtin)
#if __has_builtin(__builtin_amdgcn_permlane32_swap)
#define HAVE_PL32 1
#endif
#endif
#ifndef HAVE_PL32
#define HAVE_PL32 0
#endif

// ---- ws layout (float offsets) ----
#define WS_Q0    0          // 1024
#define WS_Q     1024       // 1024
#define WS_R     2048       // 16*1024
#define WS_C     18432      // 64 (16 used)
#define WS_CTX   19008      // 32768
#define WS_Y     51776      // 32768
#define WS_SSUM  84544      // 32*32*16 = 16384
#define WS_PART  100928     // 32*32*16*1024 = 16777216

__device__ __forceinline__ float wave_sum(float v) {
#pragma unroll
    for (int s = 32; s >= 1; s >>= 1) v += __shfl_xor(v, s, 64);
    return v;
}

// ---------------- K0: q0 = LN(symbol_queries[pos]) ----------------
__global__ void k_q0(const float* __restrict__ sq, const float* __restrict__ qn_w,
                     const float* __restrict__ qn_b, const int* __restrict__ pos,
                     float* __restrict__ ws) {
    const int t = threadIdx.x;              // 256 threads
    const float4 x = ((const float4*)(sq + (size_t)pos[0] * DD))[t];
    float s  = x.x + x.y + x.z + x.w;
    float s2 = x.x * x.x + x.y * x.y + x.z * x.z + x.w * x.w;
    __shared__ float rs[4], rs2[4];
    s = wave_sum(s); s2 = wave_sum(s2);
    const int w = t >> 6, lane = t & 63;
    if (lane == 0) { rs[w] = s; rs2[w] = s2; }
    __syncthreads();
    s  = rs[0] + rs[1] + rs[2] + rs[3];
    s2 = rs2[0] + rs2[1] + rs2[2] + rs2[3];
    const float mu  = s * (1.0f / DD);
    const float var = s2 * (1.0f / DD) - mu * mu;
    const float rstd = rsqrtf(var + 1e-5f);
    const float4 w4 = ((const float4*)qn_w)[t];
    const float4 b4 = ((const float4*)qn_b)[t];
    float4 o;
    o.x = (x.x - mu) * rstd * w4.x + b4.x;
    o.y = (x.y - mu) * rstd * w4.y + b4.y;
    o.z = (x.z - mu) * rstd * w4.z + b4.z;
    o.w = (x.w - mu) * rstd * w4.w + b4.w;
    ((float4*)(ws + WS_Q0))[t] = o;
}

// ---------------- K1: q = Wq @ q0 + bq  (wave per output) ----------------
__global__ void k_q(const float* __restrict__ ipw, const float* __restrict__ ipb,
                    float* __restrict__ ws) {
    const int w = threadIdx.x >> 6, lane = threadIdx.x & 63;
    const int d = blockIdx.x * 4 + w;       // 256 blocks * 4 waves = 1024 outputs
    const float* row = ipw + (size_t)d * DD;
    const float* q0 = ws + WS_Q0;
    float acc = 0.f;
#pragma unroll
    for (int it = 0; it < 4; ++it) {
        float4 a = ((const float4*)row)[lane + 64 * it];
        float4 b = ((const float4*)q0)[lane + 64 * it];
        acc += a.x * b.x + a.y * b.y + a.z * b.z + a.w * b.w;
    }
    acc = wave_sum(acc);
    if (lane == 0) (ws + WS_Q)[d] = acc + ipb[d];
}

// ---------------- K2: r_s[h,e] = scale * sum_j q[h,j] Wk[h*64+j, e] --------
__global__ void k_r(const float* __restrict__ ipw, const float* __restrict__ ipb,
                    float* __restrict__ ws) {
    const int h = blockIdx.x >> 2, qa = blockIdx.x & 3;
    const int t = threadIdx.x;
    const int e = qa * 256 + t;
    const float* q = ws + WS_Q;
    const float* wk = ipw + (size_t)(DD + h * DHH) * DD;
    float acc = 0.f;
#pragma unroll 8
    for (int j = 0; j < DHH; ++j)
        acc += q[h * DHH + j] * wk[(size_t)j * DD + e];
    (ws + WS_R)[h * DD + e] = acc * 0.125f;
    if (qa == 0 && t < 64) {
        float p = q[h * DHH + t] * ipb[DD + h * DHH + t];
        p = wave_sum(p);
        if (t == 0) (ws + WS_C)[h] = p * 0.125f;
    }
}

// ---------------- fused: scores + exp + weighted pooling, one grid pass ----
// block = (b, chunk of 64 rows); 256 threads; thread owns float4 e-slice.
// Pipeline: pool(g-1) | scores(g)+butterfly+red-write | BARRIER | all-wave
// combine+exp+wbuf-write.  ONE barrier per group.  Safe because each wave
// redundantly writes the full wbuf (own-wave lgkm ordering covers its reads;
// cross-wave duplicate writes carry identical values), and red/wbuf are
// double-buffered with barrier-separated epochs.
// NOTE: __launch_bounds__(256, 2) is load-bearing: 124-VGPR no-spill codegen
// (R2). (256,4) clamps to 64 VGPR and spills ~2 GB (R3).
__global__ __launch_bounds__(256, 2)
void k_fused(const float* __restrict__ gr, const float* __restrict__ ws,
             float* __restrict__ attn_e, float* __restrict__ part,
             float* __restrict__ ssum) {
    const int b  = blockIdx.x >> 5;
    const int ck = blockIdx.x & 31;
    const int l0 = ck * CH;
    const int t = threadIdx.x, w = t >> 6, lane = t & 63;
    float4 rr[16];
#pragma unroll
    for (int h = 0; h < 16; ++h) rr[h] = ((const float4*)(ws + WS_R + h * DD))[t];
    const float myc = (ws + WS_C)[lane >> 2];
    float4 acc[16];
#pragma unroll
    for (int h = 0; h < 16; ++h) acc[h] = make_float4(0.f, 0.f, 0.f, 0.f);
    float s_loc = 0.f;                      // wave0: per-lane running weight sum
    float* outp = attn_e + (size_t)b * (HH * LL) + (size_t)(lane >> 2) * LL + l0 + (lane & 3);
    const float* gb = gr + ((size_t)b * LL + l0) * DD;
    __shared__ __align__(16) float red[2][64][4];   // [buf][value][wave]
    __shared__ __align__(16) float wbuf[2][64];     // [buf][value]
    float4 gv[4], gn[4];

    auto scores_red = [&](int g) {
        float val[64];                      // v = h*4 + j
#pragma unroll
        for (int h = 0; h < 16; ++h)
#pragma unroll
            for (int j = 0; j < 4; ++j)
                val[h * 4 + j] = rr[h].x * gv[j].x + rr[h].y * gv[j].y +
                                 rr[h].z * gv[j].z + rr[h].w * gv[j].w;
#if HAVE_PL32
        // step s=32 via v_permlane32_swap: a'={a.lo,b.lo}, b'={a.hi,b.hi};
        // a'+b' = value k reduced over {l,l^32} in lanes<32, value k+32 in >=32
        // (same layout as the shfl butterfly's step 0).
#pragma unroll
        for (int k = 0; k < 32; ++k) {
            auto pr = __builtin_amdgcn_permlane32_swap(
                __float_as_uint(val[k]), __float_as_uint(val[k + 32]), false, false);
            val[k] = __uint_as_float(pr[0]) + __uint_as_float(pr[1]);
        }
#pragma unroll
        for (int step = 1; step < 6; ++step) {
            const int s = 32 >> step;
            const bool up = (lane & s) != 0;
#pragma unroll
            for (int k = 0; k < (32 >> step); ++k) {
                float send = up ? val[k] : val[k + s];
                float recv = __shfl_xor(send, s, 64);
                float mine = up ? val[k + s] : val[k];
                val[k] = mine + recv;
            }
        }
#else
#pragma unroll
        for (int step = 0; step < 6; ++step) {
            const int s = 32 >> step;
            const bool up = (lane & s) != 0;
#pragma unroll
            for (int k = 0; k < (32 >> step); ++k) {
                float send = up ? val[k] : val[k + s];
                float recv = __shfl_xor(send, s, 64);
                float mine = up ? val[k + s] : val[k];
                val[k] = mine + recv;
            }
        }
#endif
        red[g & 1][lane][w] = val[0];
    };

    auto finish = [&](int g) {              // after barrier; all waves
        const float4 pr4 = *((const float4*)red[g & 1][lane]);
        const float tot = pr4.x + pr4.y + pr4.z + pr4.w + myc;
        const float wv = __expf(tot);       // no max-shift: |score| ~ O(1)
        wbuf[g & 1][lane] = wv;             // every wave writes all 64 entries
        if (w == 0) { outp[g * 4] = wv; s_loc += wv; }
    };

    auto pool = [&](int g) {                // uses gv rows of group g
        const float* wbf = wbuf[g & 1];
#pragma unroll
        for (int h = 0; h < 16; ++h) {
            const float4 w4 = ((const float4*)wbf)[h];
            acc[h].x += w4.x * gv[0].x + w4.y * gv[1].x + w4.z * gv[2].x + w4.w * gv[3].x;
            acc[h].y += w4.x * gv[0].y + w4.y * gv[1].y + w4.z * gv[2].y + w4.w * gv[3].y;
            acc[h].z += w4.x * gv[0].z + w4.y * gv[1].z + w4.z * gv[2].z + w4.w * gv[3].z;
            acc[h].w += w4.x * gv[0].w + w4.y * gv[1].w + w4.z * gv[2].w + w4.w * gv[3].w;
        }
    };

    // ---- prologue: group 0 ----
#pragma unroll
    for (int j = 0; j < 4; ++j) gv[j] = ((const float4*)(gb + (size_t)j * DD))[t];
#pragma unroll
    for (int j = 0; j < 4; ++j) gn[j] = ((const float4*)(gb + (size_t)(4 + j) * DD))[t];
    scores_red(0);
    __syncthreads();
    finish(0);

    for (int g = 1; g < NG; ++g) {
        pool(g - 1);                        // gv still holds group g-1
#pragma unroll
        for (int j = 0; j < 4; ++j) gv[j] = gn[j];
        if (g + 1 < NG) {
#pragma unroll
            for (int j = 0; j < 4; ++j)
                gn[j] = ((const float4*)(gb + (size_t)((g + 1) * 4 + j) * DD))[t];
        }
        scores_red(g);
        __syncthreads();
        finish(g);
    }
    pool(NG - 1);

    // ---- write weight sums (w0) and partials ----
    if (w == 0) {
        float v = s_loc;
        v += __shfl_xor(v, 1, 64);
        v += __shfl_xor(v, 2, 64);
        if ((lane & 3) == 0) ssum[((size_t)b * NCK + ck) * HH + (lane >> 2)] = v;
    }
    float* pp = part + ((size_t)b * NCK + ck) * (HH * DD);
#pragma unroll
    for (int h = 0; h < 16; ++h) ((float4*)(pp + h * DD))[t] = acc[h];
}

// ---------------- combine + attn-normalize + Wv: ctx[b, h*64+j] ------------
__global__ void k_ctx(const float* __restrict__ ipw, const float* __restrict__ ipb,
                      const float* __restrict__ part, const float* __restrict__ ssum,
                      float* __restrict__ attn_e, float* __restrict__ ctx) {
    const int bh = blockIdx.x, b = bh >> 4, h = bh & 15;   // 512 blocks
    const int t = threadIdx.x, w = t >> 6, lane = t & 63;  // 256
    float S = 0.f;
#pragma unroll
    for (int c = 0; c < NCK; ++c) S += ssum[((size_t)b * NCK + c) * HH + h];
    const float inv = 1.0f / S;
    // normalize this (b,h) attn row in place
    float4* ar = (float4*)(attn_e + (size_t)bh * LL);
#pragma unroll
    for (int i = 0; i < 2; ++i) {
        float4 v = ar[t + 256 * i];
        v.x *= inv; v.y *= inv; v.z *= inv; v.w *= inv;
        ar[t + 256 * i] = v;
    }
    __shared__ float Xl[DD];
    float4 x = {0.f, 0.f, 0.f, 0.f};
#pragma unroll
    for (int c = 0; c < NCK; ++c) {
        float4 p = ((const float4*)(part + ((size_t)b * NCK + c) * (HH * DD) + h * DD))[t];
        x.x += p.x; x.y += p.y; x.z += p.z; x.w += p.w;
    }
    float4 xs = {x.x * inv, x.y * inv, x.z * inv, x.w * inv};
    ((float4*)Xl)[t] = xs;
    __syncthreads();
    for (int jj = 0; jj < 16; ++jj) {
        const int j = w * 16 + jj;
        const float* row = ipw + (size_t)(2 * DD + h * DHH + j) * DD;
        float acc = 0.f;
#pragma unroll
        for (int it = 0; it < 4; ++it) {
            float4 a = ((const float4*)row)[lane + 64 * it];
            float4 p = ((const float4*)Xl)[lane + 64 * it];
            acc += a.x * p.x + a.y * p.y + a.z * p.z + a.w * p.w;
        }
        acc = wave_sum(acc);
        if (lane == 0) ctx[(size_t)b * DD + h * DHH + j] = acc + ipb[2 * DD + h * DHH + j];
    }
}

// ---------------- y[b, d'] = out_w[d',:]·ctx[b,:] + out_b ----------------
__global__ void k_y(const float* __restrict__ ow, const float* __restrict__ ob,
                    const float* __restrict__ ctx, float* __restrict__ y) {
    const int blk = blockIdx.x, b = blk >> 4, ch = blk & 15;  // 512 blocks
    const int t = threadIdx.x, w = t >> 6, lane = t & 63;     // 256
    __shared__ float Xl[DD];
    ((float4*)Xl)[t] = ((const float4*)(ctx + (size_t)b * DD))[t];
    __syncthreads();
    for (int jj = 0; jj < 16; ++jj) {
        const int d = ch * 64 + w * 16 + jj;
        const float* row = ow + (size_t)d * DD;
        float acc = 0.f;
#pragma unroll
        for (int it = 0; it < 4; ++it) {
            float4 a = ((const float4*)row)[lane + 64 * it];
            float4 p = ((const float4*)Xl)[lane + 64 * it];
            acc += a.x * p.x + a.y * p.y + a.z * p.z + a.w * p.w;
        }
        acc = wave_sum(acc);
        if (lane == 0) y[(size_t)b * DD + d] = acc + ob[d];
    }
}

// ---------------- final LN -> pooled output ----------------
__global__ void k_lnout(const float* __restrict__ y, const float* __restrict__ on_w,
                        const float* __restrict__ on_b, float* __restrict__ outp) {
    const int b = blockIdx.x, t = threadIdx.x;   // 32 blocks, 256 threads
    const float4 x = ((const float4*)(y + (size_t)b * DD))[t];
    float s  = x.x + x.y + x.z + x.w;
    float s2 = x.x * x.x + x.y * x.y + x.z * x.z + x.w * x.w;
    __shared__ float rs[4], rs2[4];
    s = wave_sum(s); s2 = wave_sum(s2);
    const int w = t >> 6, lane = t & 63;
    if (lane == 0) { rs[w] = s; rs2[w] = s2; }
    __syncthreads();
    s  = rs[0] + rs[1] + rs[2] + rs[3];
    s2 = rs2[0] + rs2[1] + rs2[2] + rs2[3];
    const float mu  = s * (1.0f / DD);
    const float var = s2 * (1.0f / DD) - mu * mu;
    const float rstd = rsqrtf(var + 1e-5f);
    const float4 w4 = ((const float4*)on_w)[t];
    const float4 b4 = ((const float4*)on_b)[t];
    float4 o;
    o.x = (x.x - mu) * rstd * w4.x + b4.x;
    o.y = (x.y - mu) * rstd * w4.y + b4.y;
    o.z = (x.z - mu) * rstd * w4.z + b4.z;
    o.w = (x.w - mu) * rstd * w4.w + b4.w;
    ((float4*)(outp + (size_t)b * DD))[t] = o;
}

extern "C" void kernel_launch(void* const* d_in, const int* in_sizes, int n_in,
                              void* d_out, int out_size, void* d_ws, size_t ws_size,
                              hipStream_t stream) {
    const float* gr   = (const float*)d_in[0];
    const float* sq   = (const float*)d_in[1];
    const float* qn_w = (const float*)d_in[2];
    const float* qn_b = (const float*)d_in[3];
    const float* ipw  = (const float*)d_in[4];
    const float* ipb  = (const float*)d_in[5];
    const float* ow   = (const float*)d_in[6];
    const float* ob   = (const float*)d_in[7];
    const float* on_w = (const float*)d_in[8];
    const float* on_b = (const float*)d_in[9];
    const int*   pos  = (const int*)d_in[10];

    float* out  = (float*)d_out;
    float* attn = out + BB * DD;           // output 1 region; holds exp(score) until k_ctx norms
    float* ws   = (float*)d_ws;

    k_q0<<<1, 256, 0, stream>>>(sq, qn_w, qn_b, pos, ws);
    k_q<<<256, 256, 0, stream>>>(ipw, ipb, ws);
    k_r<<<64, 256, 0, stream>>>(ipw, ipb, ws);
    k_fused<<<BB * NCK, 256, 0, stream>>>(gr, ws, attn, ws + WS_PART, ws + WS_SSUM);
    k_ctx<<<BB * HH, 256, 0, stream>>>(ipw, ipb, ws + WS_PART, ws + WS_SSUM,
                                       attn, ws + WS_CTX);
    k_y<<<BB * 16, 256, 0, stream>>>(ow, ob, ws + WS_CTX, ws + WS_Y);
    k_lnout<<<BB, 256, 0, stream>>>(ws + WS_Y, on_w, on_b, out);
}

// Round 6
// 310.687 us; speedup vs baseline: 1.4988x; 1.4988x over previous
//
#include <hip/hip_runtime.h>
#include <math.h>

#define BB 32
#define LL 2048
#define DD 1024
#define HH 16
#define DHH 64
#define NCK 32         // chunks per batch
#define CH  64         // rows per chunk
#define NG  (CH / 4)   // 4-row groups per chunk

// ---- ws layout (float offsets) ----
#define WS_Q0    0          // 1024
#define WS_Q     1024       // 1024
#define WS_R     2048       // 16*1024
#define WS_C     18432      // 64 (16 used)
#define WS_CTX   19008      // 32768
#define WS_Y     51776      // 32768
#define WS_SSUM  84544      // 32*32*16 = 16384
#define WS_PART  100928     // 32*32*16*1024 = 16777216

__device__ __forceinline__ float wave_sum(float v) {
#pragma unroll
    for (int s = 32; s >= 1; s >>= 1) v += __shfl_xor(v, s, 64);
    return v;
}

// ---------------- K0: q0 = LN(symbol_queries[pos]) ----------------
__global__ void k_q0(const float* __restrict__ sq, const float* __restrict__ qn_w,
                     const float* __restrict__ qn_b, const int* __restrict__ pos,
                     float* __restrict__ ws) {
    const int t = threadIdx.x;              // 256 threads
    const float4 x = ((const float4*)(sq + (size_t)pos[0] * DD))[t];
    float s  = x.x + x.y + x.z + x.w;
    float s2 = x.x * x.x + x.y * x.y + x.z * x.z + x.w * x.w;
    __shared__ float rs[4], rs2[4];
    s = wave_sum(s); s2 = wave_sum(s2);
    const int w = t >> 6, lane = t & 63;
    if (lane == 0) { rs[w] = s; rs2[w] = s2; }
    __syncthreads();
    s  = rs[0] + rs[1] + rs[2] + rs[3];
    s2 = rs2[0] + rs2[1] + rs2[2] + rs2[3];
    const float mu  = s * (1.0f / DD);
    const float var = s2 * (1.0f / DD) - mu * mu;
    const float rstd = rsqrtf(var + 1e-5f);
    const float4 w4 = ((const float4*)qn_w)[t];
    const float4 b4 = ((const float4*)qn_b)[t];
    float4 o;
    o.x = (x.x - mu) * rstd * w4.x + b4.x;
    o.y = (x.y - mu) * rstd * w4.y + b4.y;
    o.z = (x.z - mu) * rstd * w4.z + b4.z;
    o.w = (x.w - mu) * rstd * w4.w + b4.w;
    ((float4*)(ws + WS_Q0))[t] = o;
}

// ---------------- K1: q = Wq @ q0 + bq  (wave per output) ----------------
__global__ void k_q(const float* __restrict__ ipw, const float* __restrict__ ipb,
                    float* __restrict__ ws) {
    const int w = threadIdx.x >> 6, lane = threadIdx.x & 63;
    const int d = blockIdx.x * 4 + w;       // 256 blocks * 4 waves = 1024 outputs
    const float* row = ipw + (size_t)d * DD;
    const float* q0 = ws + WS_Q0;
    float acc = 0.f;
#pragma unroll
    for (int it = 0; it < 4; ++it) {
        float4 a = ((const float4*)row)[lane + 64 * it];
        float4 b = ((const float4*)q0)[lane + 64 * it];
        acc += a.x * b.x + a.y * b.y + a.z * b.z + a.w * b.w;
    }
    acc = wave_sum(acc);
    if (lane == 0) (ws + WS_Q)[d] = acc + ipb[d];
}

// ---------------- K2: r_s[h,e] = scale * sum_j q[h,j] Wk[h*64+j, e] --------
__global__ void k_r(const float* __restrict__ ipw, const float* __restrict__ ipb,
                    float* __restrict__ ws) {
    const int h = blockIdx.x >> 2, qa = blockIdx.x & 3;
    const int t = threadIdx.x;
    const int e = qa * 256 + t;
    const float* q = ws + WS_Q;
    const float* wk = ipw + (size_t)(DD + h * DHH) * DD;
    float acc = 0.f;
#pragma unroll 8
    for (int j = 0; j < DHH; ++j)
        acc += q[h * DHH + j] * wk[(size_t)j * DD + e];
    (ws + WS_R)[h * DD + e] = acc * 0.125f;
    if (qa == 0 && t < 64) {
        float p = q[h * DHH + t] * ipb[DD + h * DHH + t];
        p = wave_sum(p);
        if (t == 0) (ws + WS_C)[h] = p * 0.125f;
    }
}

// ---------------- fused: scores + exp + weighted pooling, one grid pass ----
// block = (b, chunk of 64 rows); 256 threads; thread owns float4 e-slice.
// ONE barrier per group:
//   scores_red(g) -> red[g&1][w][lane]  (stride-1, conflict-free)
//   BARRIER
//   finish(g): ALL waves read red, exp, write PRIVATE wbuf[g&1][w][lane]
//   prefetch(g+1)  (val[64] dead here -- keeps R4's 124-VGPR schedule)
//   pool(g) reads own wave's wbuf  (own-wave lgkm ordering, no 2nd barrier)
// red is 2-deep: a wave can only be one group ahead before the next barrier,
// so red[g&1] is never overwritten before all waves consumed it.
// NOTE: __launch_bounds__(256, 2) is load-bearing: 124-VGPR no-spill codegen
// (R2/R4). (256,4) clamps to 64 VGPR and spills ~2 GB (R3).
__global__ __launch_bounds__(256, 2)
void k_fused(const float* __restrict__ gr, const float* __restrict__ ws,
             float* __restrict__ attn_e, float* __restrict__ part,
             float* __restrict__ ssum) {
    const int b  = blockIdx.x >> 5;
    const int ck = blockIdx.x & 31;
    const int l0 = ck * CH;
    const int t = threadIdx.x, w = t >> 6, lane = t & 63;
    float4 rr[16];
#pragma unroll
    for (int h = 0; h < 16; ++h) rr[h] = ((const float4*)(ws + WS_R + h * DD))[t];
    const float myc = (ws + WS_C)[lane >> 2];
    float4 acc[16];
#pragma unroll
    for (int h = 0; h < 16; ++h) acc[h] = make_float4(0.f, 0.f, 0.f, 0.f);
    float s_loc = 0.f;                      // wave0: per-lane running weight sum
    float* outp = attn_e + (size_t)b * (HH * LL) + (size_t)(lane >> 2) * LL + l0 + (lane & 3);
    const float* gb = gr + ((size_t)b * LL + l0) * DD;
    __shared__ float red[2][4][64];         // [buf][wave][value] -- stride-1 per lane
    __shared__ float wbuf[2][4][64];        // [buf][wave][value] -- per-wave private
    float4 gv[4], gn[4];

    auto scores_red = [&](int g) {
        float val[64];                      // v = h*4 + j
#pragma unroll
        for (int h = 0; h < 16; ++h)
#pragma unroll
            for (int j = 0; j < 4; ++j)
                val[h * 4 + j] = rr[h].x * gv[j].x + rr[h].y * gv[j].y +
                                 rr[h].z * gv[j].z + rr[h].w * gv[j].w;
        // multi-value butterfly: lane i ends holding total of value i
#pragma unroll
        for (int step = 0; step < 6; ++step) {
            const int s = 32 >> step;
            const bool up = (lane & s) != 0;
#pragma unroll
            for (int k = 0; k < (32 >> step); ++k) {
                float send = up ? val[k] : val[k + s];
                float recv = __shfl_xor(send, s, 64);
                float mine = up ? val[k + s] : val[k];
                val[k] = mine + recv;
            }
        }
        red[g & 1][w][lane] = val[0];
    };

    auto finish = [&](int g) {              // after barrier; all waves
        const float* rd0 = red[g & 1][0];
        const float tot = rd0[lane] + rd0[64 + lane] + rd0[128 + lane] +
                          rd0[192 + lane] + myc;
        const float wv = __expf(tot);       // no max-shift: |score| ~ O(1)
        wbuf[g & 1][w][lane] = wv;          // private per-wave copy
        if (w == 0) { outp[g * 4] = wv; s_loc += wv; }
    };

    auto pool = [&](int g) {                // uses gv rows of group g
        const float* wbf = wbuf[g & 1][w];
#pragma unroll
        for (int h = 0; h < 16; ++h) {
            const float4 w4 = ((const float4*)wbf)[h];
            acc[h].x += w4.x * gv[0].x + w4.y * gv[1].x + w4.z * gv[2].x + w4.w * gv[3].x;
            acc[h].y += w4.x * gv[0].y + w4.y * gv[1].y + w4.z * gv[2].y + w4.w * gv[3].y;
            acc[h].z += w4.x * gv[0].z + w4.y * gv[1].z + w4.z * gv[2].z + w4.w * gv[3].z;
            acc[h].w += w4.x * gv[0].w + w4.y * gv[1].w + w4.z * gv[2].w + w4.w * gv[3].w;
        }
    };

    // ---- prologue ----
#pragma unroll
    for (int j = 0; j < 4; ++j) gv[j] = ((const float4*)(gb + (size_t)j * DD))[t];
    scores_red(0);

    for (int g = 0; g < NG; ++g) {
        __syncthreads();
        finish(g);
        if (g + 1 < NG) {                   // prefetch AFTER scores (val dead)
#pragma unroll
            for (int j = 0; j < 4; ++j)
                gn[j] = ((const float4*)(gb + (size_t)((g + 1) * 4 + j) * DD))[t];
        }
        pool(g);
        if (g + 1 < NG) {
#pragma unroll
            for (int j = 0; j < 4; ++j) gv[j] = gn[j];
            scores_red(g + 1);
        }
    }

    // ---- write weight sums (w0) and partials ----
    if (w == 0) {
        float v = s_loc;
        v += __shfl_xor(v, 1, 64);
        v += __shfl_xor(v, 2, 64);
        if ((lane & 3) == 0) ssum[((size_t)b * NCK + ck) * HH + (lane >> 2)] = v;
    }
    float* pp = part + ((size_t)b * NCK + ck) * (HH * DD);
#pragma unroll
    for (int h = 0; h < 16; ++h) ((float4*)(pp + h * DD))[t] = acc[h];
}

// ---------------- combine + attn-normalize + Wv: ctx[b, h*64+j] ------------
__global__ void k_ctx(const float* __restrict__ ipw, const float* __restrict__ ipb,
                      const float* __restrict__ part, const float* __restrict__ ssum,
                      float* __restrict__ attn_e, float* __restrict__ ctx) {
    const int bh = blockIdx.x, b = bh >> 4, h = bh & 15;   // 512 blocks
    const int t = threadIdx.x, w = t >> 6, lane = t & 63;  // 256
    float S = 0.f;
#pragma unroll
    for (int c = 0; c < NCK; ++c) S += ssum[((size_t)b * NCK + c) * HH + h];
    const float inv = 1.0f / S;
    // normalize this (b,h) attn row in place
    float4* ar = (float4*)(attn_e + (size_t)bh * LL);
#pragma unroll
    for (int i = 0; i < 2; ++i) {
        float4 v = ar[t + 256 * i];
        v.x *= inv; v.y *= inv; v.z *= inv; v.w *= inv;
        ar[t + 256 * i] = v;
    }
    __shared__ float Xl[DD];
    float4 x = {0.f, 0.f, 0.f, 0.f};
#pragma unroll
    for (int c = 0; c < NCK; ++c) {
        float4 p = ((const float4*)(part + ((size_t)b * NCK + c) * (HH * DD) + h * DD))[t];
        x.x += p.x; x.y += p.y; x.z += p.z; x.w += p.w;
    }
    float4 xs = {x.x * inv, x.y * inv, x.z * inv, x.w * inv};
    ((float4*)Xl)[t] = xs;
    __syncthreads();
    for (int jj = 0; jj < 16; ++jj) {
        const int j = w * 16 + jj;
        const float* row = ipw + (size_t)(2 * DD + h * DHH + j) * DD;
        float acc = 0.f;
#pragma unroll
        for (int it = 0; it < 4; ++it) {
            float4 a = ((const float4*)row)[lane + 64 * it];
            float4 p = ((const float4*)Xl)[lane + 64 * it];
            acc += a.x * p.x + a.y * p.y + a.z * p.z + a.w * p.w;
        }
        acc = wave_sum(acc);
        if (lane == 0) ctx[(size_t)b * DD + h * DHH + j] = acc + ipb[2 * DD + h * DHH + j];
    }
}

// ---------------- y[b, d'] = out_w[d',:]·ctx[b,:] + out_b ----------------
__global__ void k_y(const float* __restrict__ ow, const float* __restrict__ ob,
                    const float* __restrict__ ctx, float* __restrict__ y) {
    const int blk = blockIdx.x, b = blk >> 4, ch = blk & 15;  // 512 blocks
    const int t = threadIdx.x, w = t >> 6, lane = t & 63;     // 256
    __shared__ float Xl[DD];
    ((float4*)Xl)[t] = ((const float4*)(ctx + (size_t)b * DD))[t];
    __syncthreads();
    for (int jj = 0; jj < 16; ++jj) {
        const int d = ch * 64 + w * 16 + jj;
        const float* row = ow + (size_t)d * DD;
        float acc = 0.f;
#pragma unroll
        for (int it = 0; it < 4; ++it) {
            float4 a = ((const float4*)row)[lane + 64 * it];
            float4 p = ((const float4*)Xl)[lane + 64 * it];
            acc += a.x * p.x + a.y * p.y + a.z * p.z + a.w * p.w;
        }
        acc = wave_sum(acc);
        if (lane == 0) y[(size_t)b * DD + d] = acc + ob[d];
    }
}

// ---------------- final LN -> pooled output ----------------
__global__ void k_lnout(const float* __restrict__ y, const float* __restrict__ on_w,
                        const float* __restrict__ on_b, float* __restrict__ outp) {
    const int b = blockIdx.x, t = threadIdx.x;   // 32 blocks, 256 threads
    const float4 x = ((const float4*)(y + (size_t)b * DD))[t];
    float s  = x.x + x.y + x.z + x.w;
    float s2 = x.x * x.x + x.y * x.y + x.z * x.z + x.w * x.w;
    __shared__ float rs[4], rs2[4];
    s = wave_sum(s); s2 = wave_sum(s2);
    const int w = t >> 6, lane = t & 63;
    if (lane == 0) { rs[w] = s; rs2[w] = s2; }
    __syncthreads();
    s  = rs[0] + rs[1] + rs[2] + rs[3];
    s2 = rs2[0] + rs2[1] + rs2[2] + rs2[3];
    const float mu  = s * (1.0f / DD);
    const float var = s2 * (1.0f / DD) - mu * mu;
    const float rstd = rsqrtf(var + 1e-5f);
    const float4 w4 = ((const float4*)on_w)[t];
    const float4 b4 = ((const float4*)on_b)[t];
    float4 o;
    o.x = (x.x - mu) * rstd * w4.x + b4.x;
    o.y = (x.y - mu) * rstd * w4.y + b4.y;
    o.z = (x.z - mu) * rstd * w4.z + b4.z;
    o.w = (x.w - mu) * rstd * w4.w + b4.w;
    ((float4*)(outp + (size_t)b * DD))[t] = o;
}

extern "C" void kernel_launch(void* const* d_in, const int* in_sizes, int n_in,
                              void* d_out, int out_size, void* d_ws, size_t ws_size,
                              hipStream_t stream) {
    const float* gr   = (const float*)d_in[0];
    const float* sq   = (const float*)d_in[1];
    const float* qn_w = (const float*)d_in[2];
    const float* qn_b = (const float*)d_in[3];
    const float* ipw  = (const float*)d_in[4];
    const float* ipb  = (const float*)d_in[5];
    const float* ow   = (const float*)d_in[6];
    const float* ob   = (const float*)d_in[7];
    const float* on_w = (const float*)d_in[8];
    const float* on_b = (const float*)d_in[9];
    const int*   pos  = (const int*)d_in[10];

    float* out  = (float*)d_out;
    float* attn = out + BB * DD;           // output 1 region; holds exp(score) until k_ctx norms
    float* ws   = (float*)d_ws;

    k_q0<<<1, 256, 0, stream>>>(sq, qn_w, qn_b, pos, ws);
    k_q<<<256, 256, 0, stream>>>(ipw, ipb, ws);
    k_r<<<64, 256, 0, stream>>>(ipw, ipb, ws);
    k_fused<<<BB * NCK, 256, 0, stream>>>(gr, ws, attn, ws + WS_PART, ws + WS_SSUM);
    k_ctx<<<BB * HH, 256, 0, stream>>>(ipw, ipb, ws + WS_PART, ws + WS_SSUM,
                                       attn, ws + WS_CTX);
    k_y<<<BB * 16, 256, 0, stream>>>(ow, ob, ws + WS_CTX, ws + WS_Y);
    k_lnout<<<BB, 256, 0, stream>>>(ws + WS_Y, on_w, on_b, out);
}

// Round 8
// 125.537 us; speedup vs baseline: 3.7094x; 2.4749x over previous
//
#include <hip/hip_runtime.h>
#include <math.h>

#define BB 32
#define LL 2048
#define DD 1024
#define HH 16
#define DHH 64
#define NCK 16         // chunks per batch
#define CH  128        // rows per chunk (4 tiles of 32)

// ---- ws layout (float offsets) ----
#define WS_Q0    0          // 1024
#define WS_Q     1024       // 1024
#define WS_R     2048       // 16*1024
#define WS_C     18432      // 64 (16 used)
#define WS_CTX   19008      // 32768
#define WS_Y     51776      // 32768
#define WS_SSUM  84544      // 32*16*16 = 8192
#define WS_PART  92736      // 32*16*16*1024 = 8388608

// ---- k_fused dynamic LDS layout (bytes) ----
#define G_OFF    0          // 32 rows x 1024 e bf16, [4][16]-subtiled = 65536
#define RED_OFF  65536      // 4 waves x 64 lanes x 8 f32 = 8192
#define WT_OFF   73728      // 4 waves x 16 h x 32 l bf16 = 4096
#define SMEM_BYTES 77824

typedef __attribute__((ext_vector_type(8))) short    bf16x8;
typedef __attribute__((ext_vector_type(4))) float    f32x4;
typedef __attribute__((ext_vector_type(2))) unsigned u32x2;
typedef __attribute__((ext_vector_type(4))) unsigned short u16x4;

#define MFMA(a, b, c) __builtin_amdgcn_mfma_f32_16x16x32_bf16(a, b, c, 0, 0, 0)

__device__ __forceinline__ unsigned short f2bf(float f) {   // RNE f32->bf16
    unsigned u = __float_as_uint(f);
    return (unsigned short)((u + 0x7FFFu + ((u >> 16) & 1u)) >> 16);
}
__device__ __forceinline__ bf16x8 pack8(float4 a, float4 b) {
    bf16x8 r;
    r[0] = (short)f2bf(a.x); r[1] = (short)f2bf(a.y);
    r[2] = (short)f2bf(a.z); r[3] = (short)f2bf(a.w);
    r[4] = (short)f2bf(b.x); r[5] = (short)f2bf(b.y);
    r[6] = (short)f2bf(b.z); r[7] = (short)f2bf(b.w);
    return r;
}
__device__ __forceinline__ float wave_sum(float v) {
#pragma unroll
    for (int s = 32; s >= 1; s >>= 1) v += __shfl_xor(v, s, 64);
    return v;
}

// ---------------- K0: q0 = LN(symbol_queries[pos]) ----------------
__global__ void k_q0(const float* __restrict__ sq, const float* __restrict__ qn_w,
                     const float* __restrict__ qn_b, const int* __restrict__ pos,
                     float* __restrict__ ws) {
    const int t = threadIdx.x;              // 256 threads
    const float4 x = ((const float4*)(sq + (size_t)pos[0] * DD))[t];
    float s  = x.x + x.y + x.z + x.w;
    float s2 = x.x * x.x + x.y * x.y + x.z * x.z + x.w * x.w;
    __shared__ float rs[4], rs2[4];
    s = wave_sum(s); s2 = wave_sum(s2);
    const int w = t >> 6, lane = t & 63;
    if (lane == 0) { rs[w] = s; rs2[w] = s2; }
    __syncthreads();
    s  = rs[0] + rs[1] + rs[2] + rs[3];
    s2 = rs2[0] + rs2[1] + rs2[2] + rs2[3];
    const float mu  = s * (1.0f / DD);
    const float var = s2 * (1.0f / DD) - mu * mu;
    const float rstd = rsqrtf(var + 1e-5f);
    const float4 w4 = ((const float4*)qn_w)[t];
    const float4 b4 = ((const float4*)qn_b)[t];
    float4 o;
    o.x = (x.x - mu) * rstd * w4.x + b4.x;
    o.y = (x.y - mu) * rstd * w4.y + b4.y;
    o.z = (x.z - mu) * rstd * w4.z + b4.z;
    o.w = (x.w - mu) * rstd * w4.w + b4.w;
    ((float4*)(ws + WS_Q0))[t] = o;
}

// ---------------- K1: q = Wq @ q0 + bq  (wave per output) ----------------
__global__ void k_q(const float* __restrict__ ipw, const float* __restrict__ ipb,
                    float* __restrict__ ws) {
    const int w = threadIdx.x >> 6, lane = threadIdx.x & 63;
    const int d = blockIdx.x * 4 + w;
    const float* row = ipw + (size_t)d * DD;
    const float* q0 = ws + WS_Q0;
    float acc = 0.f;
#pragma unroll
    for (int it = 0; it < 4; ++it) {
        float4 a = ((const float4*)row)[lane + 64 * it];
        float4 b = ((const float4*)q0)[lane + 64 * it];
        acc += a.x * b.x + a.y * b.y + a.z * b.z + a.w * b.w;
    }
    acc = wave_sum(acc);
    if (lane == 0) (ws + WS_Q)[d] = acc + ipb[d];
}

// ---------------- K2: r_s[h,e] = scale * sum_j q[h,j] Wk[h*64+j, e] --------
__global__ void k_r(const float* __restrict__ ipw, const float* __restrict__ ipb,
                    float* __restrict__ ws) {
    const int h = blockIdx.x >> 2, qa = blockIdx.x & 3;
    const int t = threadIdx.x;
    const int e = qa * 256 + t;
    const float* q = ws + WS_Q;
    const float* wk = ipw + (size_t)(DD + h * DHH) * DD;
    float acc = 0.f;
#pragma unroll 8
    for (int j = 0; j < DHH; ++j)
        acc += q[h * DHH + j] * wk[(size_t)j * DD + e];
    (ws + WS_R)[h * DD + e] = acc * 0.125f;
    if (qa == 0 && t < 64) {
        float p = q[h * DHH + t] * ipb[DD + h * DHH + t];
        p = wave_sum(p);
        if (t == 0) (ws + WS_C)[h] = p * 0.125f;
    }
}

// ---------------- fused MFMA: scores + exp + weighted pooling --------------
// block = (b, 128-row chunk), 4 waves; per 32-row tile:
//   stage G f32->bf16 into LDS, [4 l][16 e]-subtiled:
//     elem(l,e) = ((e>>4)*8 + (l>>2))*64 + (l&3)*16 + (e&15)
//   scores: D[m=lrow, n=h] = G @ r   (A: ds_read_b128; B: r in VGPRs)
//   cross-wave reduce (each wave owns a 256-e strip) -> exp -> w
//   PV: D[m=h, n=e] = w @ G  (A: w_t per-wave LDS; B: ds_read_b64_tr_b16)
// tr_read addressing (m156/m162): within each 16-lane group, lane i passes
// tile_base + i*8 BYTES (its own 8-byte chunk of the 128-byte 4x16 tile);
// delivered: lane i elem j = tile[row j][col i].  <-- R6 bug was i*2.
// MFMA frag convention (A: m=lane&15, k=(lane>>4)*8+i; B: n=lane&15, same k;
// C/D: col=lane&15, row=(lane>>4)*4+reg  [HW-verified]).
__global__ __launch_bounds__(256, 2)
void k_fused(const float* __restrict__ gr, const float* __restrict__ ws,
             float* __restrict__ attn_e, float* __restrict__ part,
             float* __restrict__ ssum) {
    extern __shared__ char smem[];
    const int b  = blockIdx.x >> 4;
    const int ck = blockIdx.x & 15;
    const int l0 = ck * CH;
    const int t  = threadIdx.x;
    const int wv = t >> 6, lane = t & 63;
    const int c16 = lane & 15, g = lane >> 4;
    const int estrip = wv * 256;            // this wave's e-strip

    // ---- prologue: pack r into B-frags (8 k-steps x 32 e), bias ----
    bf16x8 rpk[8];
#pragma unroll
    for (int ks = 0; ks < 8; ++ks) {
        const float* rp = ws + WS_R + (size_t)c16 * DD + estrip + ks * 32 + g * 8;
        rpk[ks] = pack8(*(const float4*)rp, *(const float4*)(rp + 4));
    }
    const float myc = (ws + WS_C)[c16];

    f32x4 pv[16];
#pragma unroll
    for (int i = 0; i < 16; ++i) pv[i] = (f32x4){0.f, 0.f, 0.f, 0.f};
    float s_acc = 0.f;

    const int srow = t >> 3;                // staging: row 0..31
    const int se0  = (t & 7) * 128;         // staging: e base

    for (int tt = 0; tt < CH / 32; ++tt) {
        if (tt) __syncthreads();            // G_lds free (prev PV done)
        // ---- stage 32 rows f32 -> bf16 subtiled ----
        const float* gsrc = gr + (size_t)(b * LL + l0 + tt * 32 + srow) * DD + se0;
#pragma unroll
        for (int j = 0; j < 16; ++j) {
            float4 f0 = *(const float4*)(gsrc + j * 8);
            float4 f1 = *(const float4*)(gsrc + j * 8 + 4);
            const int e = se0 + j * 8;
            const int elem = ((e >> 4) * 8 + (srow >> 2)) * 64 + (srow & 3) * 16 + (e & 15);
            *(bf16x8*)(smem + elem * 2) = pack8(f0, f1);
        }
        __syncthreads();                    // stage visible
        // ---- scores: 2 M-tiles (32 rows) x 8 k-steps over this wave's strip ----
        f32x4 sa0 = {0.f, 0.f, 0.f, 0.f}, sa1 = {0.f, 0.f, 0.f, 0.f};
#pragma unroll
        for (int ks = 0; ks < 8; ++ks) {
            const int e16  = wv * 16 + ks * 2 + (g >> 1);            // e>>4
            const int base = (e16 * 8 + (c16 >> 2)) * 64 + (c16 & 3) * 16 + (g & 1) * 8;
            bf16x8 a0 = *(const bf16x8*)(smem + base * 2);           // rows 0-15
            bf16x8 a1 = *(const bf16x8*)(smem + (base + 256) * 2);   // rows 16-31
            sa0 = MFMA(a0, rpk[ks], sa0);
            sa1 = MFMA(a1, rpk[ks], sa1);
        }
        float* redp = (float*)(smem + RED_OFF) + (wv * 64 + lane) * 8;
        *(f32x4*)redp = sa0;
        *(f32x4*)(redp + 4) = sa1;
        __syncthreads();                    // red visible
        // ---- finish: sum 4 wave-partials + bias, exp ----
        f32x4 t0 = {myc, myc, myc, myc}, t1 = t0;
#pragma unroll
        for (int w2 = 0; w2 < 4; ++w2) {
            const float* rq = (const float*)(smem + RED_OFF) + (w2 * 64 + lane) * 8;
            t0 += *(const f32x4*)rq;
            t1 += *(const f32x4*)(rq + 4);
        }
        f32x4 e0, e1;                       // no max-shift: |score| ~ O(1)
        e0[0] = __expf(t0[0]); e0[1] = __expf(t0[1]);
        e0[2] = __expf(t0[2]); e0[3] = __expf(t0[3]);
        e1[0] = __expf(t1[0]); e1[1] = __expf(t1[1]);
        e1[2] = __expf(t1[2]); e1[3] = __expf(t1[3]);
        // w_t (per-wave private copy; own-wave lgkm ordering -> no barrier)
        u16x4 p0 = {f2bf(e0[0]), f2bf(e0[1]), f2bf(e0[2]), f2bf(e0[3])};
        u16x4 p1 = {f2bf(e1[0]), f2bf(e1[1]), f2bf(e1[2]), f2bf(e1[3])};
        char* wtp = smem + WT_OFF + wv * 1024 + c16 * 64;
        *(u16x4*)(wtp + g * 8) = p0;        // rows g*4..g*4+3
        *(u16x4*)(wtp + 32 + g * 8) = p1;   // rows 16+g*4..
        if (wv == 0) {                      // attn (unnormalized exp) store
            float* ap = attn_e + ((size_t)b * HH + c16) * LL + l0 + tt * 32 + g * 4;
            *(float4*)ap        = make_float4(e0[0], e0[1], e0[2], e0[3]);
            *(float4*)(ap + 16) = make_float4(e1[0], e1[1], e1[2], e1[3]);
        }
        s_acc += e0[0] + e0[1] + e0[2] + e0[3] + e1[0] + e1[1] + e1[2] + e1[3];
        // ---- PV: A = w_t[h][l 0..31], B = G via hw-transpose reads ----
        bf16x8 afrag = *(const bf16x8*)(smem + WT_OFF + wv * 1024 + c16 * 64 + g * 16);
#pragma unroll
        for (int grp = 0; grp < 4; ++grp) {
            u32x2 q[8];
#pragma unroll
            for (int n2 = 0; n2 < 4; ++n2) {
                const int est = wv * 16 + grp * 4 + n2;              // e16 of n-tile
                // tile_base (bytes) = est*1024 + (g*2)*128; lane chunk = c16*8
                const unsigned ta = (unsigned)(est * 1024 + g * 256 + c16 * 8);
                asm volatile("ds_read_b64_tr_b16 %0, %1"
                             : "=v"(q[n2 * 2]) : "v"(ta));
                asm volatile("ds_read_b64_tr_b16 %0, %1 offset:128"
                             : "=v"(q[n2 * 2 + 1]) : "v"(ta));
            }
            asm volatile("s_waitcnt lgkmcnt(0)" ::: "memory");
            __builtin_amdgcn_sched_barrier(0);
#pragma unroll
            for (int n2 = 0; n2 < 4; ++n2) {
                union { unsigned u[4]; bf16x8 v; } bb;
                bb.u[0] = q[n2 * 2][0];     bb.u[1] = q[n2 * 2][1];
                bb.u[2] = q[n2 * 2 + 1][0]; bb.u[3] = q[n2 * 2 + 1][1];
                pv[grp * 4 + n2] = MFMA(afrag, bb.v, pv[grp * 4 + n2]);
            }
        }
    }
    // ---- epilogue: ssum + partials ----
    float sv = s_acc;
    sv += __shfl_xor(sv, 16, 64);
    sv += __shfl_xor(sv, 32, 64);
    if (wv == 0 && lane < 16)
        ssum[((size_t)b * NCK + ck) * HH + c16] = sv;
    float* pp = part + ((size_t)b * NCK + ck) * (HH * DD);
#pragma unroll
    for (int nt = 0; nt < 16; ++nt) {
#pragma unroll
        for (int r2 = 0; r2 < 4; ++r2)
            pp[(size_t)(g * 4 + r2) * DD + estrip + nt * 16 + c16] = pv[nt][r2];
    }
}

// ---------------- combine + attn-normalize + Wv: ctx[b, h*64+j] ------------
__global__ void k_ctx(const float* __restrict__ ipw, const float* __restrict__ ipb,
                      const float* __restrict__ part, const float* __restrict__ ssum,
                      float* __restrict__ attn_e, float* __restrict__ ctx) {
    const int bh = blockIdx.x, b = bh >> 4, h = bh & 15;   // 512 blocks
    const int t = threadIdx.x, w = t >> 6, lane = t & 63;  // 256
    float S = 0.f;
#pragma unroll
    for (int c = 0; c < NCK; ++c) S += ssum[((size_t)b * NCK + c) * HH + h];
    const float inv = 1.0f / S;
    float4* ar = (float4*)(attn_e + (size_t)bh * LL);
#pragma unroll
    for (int i = 0; i < 2; ++i) {
        float4 v = ar[t + 256 * i];
        v.x *= inv; v.y *= inv; v.z *= inv; v.w *= inv;
        ar[t + 256 * i] = v;
    }
    __shared__ float Xl[DD];
    float4 x = {0.f, 0.f, 0.f, 0.f};
#pragma unroll
    for (int c = 0; c < NCK; ++c) {
        float4 p = ((const float4*)(part + ((size_t)b * NCK + c) * (HH * DD) + h * DD))[t];
        x.x += p.x; x.y += p.y; x.z += p.z; x.w += p.w;
    }
    float4 xs = {x.x * inv, x.y * inv, x.z * inv, x.w * inv};
    ((float4*)Xl)[t] = xs;
    __syncthreads();
    for (int jj = 0; jj < 16; ++jj) {
        const int j = w * 16 + jj;
        const float* row = ipw + (size_t)(2 * DD + h * DHH + j) * DD;
        float acc = 0.f;
#pragma unroll
        for (int it = 0; it < 4; ++it) {
            float4 a = ((const float4*)row)[lane + 64 * it];
            float4 p = ((const float4*)Xl)[lane + 64 * it];
            acc += a.x * p.x + a.y * p.y + a.z * p.z + a.w * p.w;
        }
        acc = wave_sum(acc);
        if (lane == 0) ctx[(size_t)b * DD + h * DHH + j] = acc + ipb[2 * DD + h * DHH + j];
    }
}

// ---------------- y[b, d'] = out_w[d',:]·ctx[b,:] + out_b ----------------
__global__ void k_y(const float* __restrict__ ow, const float* __restrict__ ob,
                    const float* __restrict__ ctx, float* __restrict__ y) {
    const int blk = blockIdx.x, b = blk >> 4, ch = blk & 15;  // 512 blocks
    const int t = threadIdx.x, w = t >> 6, lane = t & 63;     // 256
    __shared__ float Xl[DD];
    ((float4*)Xl)[t] = ((const float4*)(ctx + (size_t)b * DD))[t];
    __syncthreads();
    for (int jj = 0; jj < 16; ++jj) {
        const int d = ch * 64 + w * 16 + jj;
        const float* row = ow + (size_t)d * DD;
        float acc = 0.f;
#pragma unroll
        for (int it = 0; it < 4; ++it) {
            float4 a = ((const float4*)row)[lane + 64 * it];
            float4 p = ((const float4*)Xl)[lane + 64 * it];
            acc += a.x * p.x + a.y * p.y + a.z * p.z + a.w * p.w;
        }
        acc = wave_sum(acc);
        if (lane == 0) y[(size_t)b * DD + d] = acc + ob[d];
    }
}

// ---------------- final LN -> pooled output ----------------
__global__ void k_lnout(const float* __restrict__ y, const float* __restrict__ on_w,
                        const float* __restrict__ on_b, float* __restrict__ outp) {
    const int b = blockIdx.x, t = threadIdx.x;   // 32 blocks, 256 threads
    const float4 x = ((const float4*)(y + (size_t)b * DD))[t];
    float s  = x.x + x.y + x.z + x.w;
    float s2 = x.x * x.x + x.y * x.y + x.z * x.z + x.w * x.w;
    __shared__ float rs[4], rs2[4];
    s = wave_sum(s); s2 = wave_sum(s2);
    const int w = t >> 6, lane = t & 63;
    if (lane == 0) { rs[w] = s; rs2[w] = s2; }
    __syncthreads();
    s  = rs[0] + rs[1] + rs[2] + rs[3];
    s2 = rs2[0] + rs2[1] + rs2[2] + rs2[3];
    const float mu  = s * (1.0f / DD);
    const float var = s2 * (1.0f / DD) - mu * mu;
    const float rstd = rsqrtf(var + 1e-5f);
    const float4 w4 = ((const float4*)on_w)[t];
    const float4 b4 = ((const float4*)on_b)[t];
    float4 o;
    o.x = (x.x - mu) * rstd * w4.x + b4.x;
    o.y = (x.y - mu) * rstd * w4.y + b4.y;
    o.z = (x.z - mu) * rstd * w4.z + b4.z;
    o.w = (x.w - mu) * rstd * w4.w + b4.w;
    ((float4*)(outp + (size_t)b * DD))[t] = o;
}

extern "C" void kernel_launch(void* const* d_in, const int* in_sizes, int n_in,
                              void* d_out, int out_size, void* d_ws, size_t ws_size,
                              hipStream_t stream) {
    const float* gr   = (const float*)d_in[0];
    const float* sq   = (const float*)d_in[1];
    const float* qn_w = (const float*)d_in[2];
    const float* qn_b = (const float*)d_in[3];
    const float* ipw  = (const float*)d_in[4];
    const float* ipb  = (const float*)d_in[5];
    const float* ow   = (const float*)d_in[6];
    const float* ob   = (const float*)d_in[7];
    const float* on_w = (const float*)d_in[8];
    const float* on_b = (const float*)d_in[9];
    const int*   pos  = (const int*)d_in[10];

    float* out  = (float*)d_out;
    float* attn = out + BB * DD;           // output 1; holds exp(score) until k_ctx norms
    float* ws   = (float*)d_ws;

    // allow 76 KB dynamic LDS for k_fused (idempotent, deterministic)
    hipFuncSetAttribute((const void*)k_fused,
                        hipFuncAttributeMaxDynamicSharedMemorySize, SMEM_BYTES);

    k_q0<<<1, 256, 0, stream>>>(sq, qn_w, qn_b, pos, ws);
    k_q<<<256, 256, 0, stream>>>(ipw, ipb, ws);
    k_r<<<64, 256, 0, stream>>>(ipw, ipb, ws);
    k_fused<<<BB * NCK, 256, SMEM_BYTES, stream>>>(gr, ws, attn,
                                                   ws + WS_PART, ws + WS_SSUM);
    k_ctx<<<BB * HH, 256, 0, stream>>>(ipw, ipb, ws + WS_PART, ws + WS_SSUM,
                                       attn, ws + WS_CTX);
    k_y<<<BB * 16, 256, 0, stream>>>(ow, ob, ws + WS_CTX, ws + WS_Y);
    k_lnout<<<BB, 256, 0, stream>>>(ws + WS_Y, on_w, on_b, out);
}

// Round 9
// 114.564 us; speedup vs baseline: 4.0647x; 1.0958x over previous
//
#include <hip/hip_runtime.h>
#include <math.h>

#define BB 32
#define LL 2048
#define DD 1024
#define HH 16
#define DHH 64
#define NCK 16         // chunks per batch
#define CH  128        // rows per chunk
#define NT  8          // 16-row tiles per chunk

// ---- ws layout (float offsets) ----
#define WS_Q0    0          // 1024
#define WS_Q     1024       // 1024
#define WS_R     2048       // 16*1024
#define WS_C     18432      // 64 (16 used)
#define WS_CTX   19008      // 32768
#define WS_Y     51776      // 32768
#define WS_SSUM  84544      // 32*16*16 = 8192
#define WS_PART  92736      // 32*16*16*1024 = 8388608

// ---- k_fused dynamic LDS layout (bytes) ----
// G tile buffers: 2 x (16 rows x 1024 e bf16, [4 l][16 e]-subtiled) = 2x32768
//   elem(l,e) = ((e>>4)*4 + (l>>2))*64 + (l&3)*16 + (e&15)
#define RED_OFF  65536      // 4 waves x 64 lanes x 4 f32 = 4096
#define WT_OFF   69632      // 4 waves x 16 h x 16 l bf16 = 2048
#define SMEM_BYTES 71680

typedef __attribute__((ext_vector_type(8))) short    bf16x8;
typedef __attribute__((ext_vector_type(4))) float    f32x4;
typedef __attribute__((ext_vector_type(2))) unsigned u32x2;
typedef __attribute__((ext_vector_type(4))) unsigned short u16x4;

#define MFMA(a, b, c) __builtin_amdgcn_mfma_f32_16x16x32_bf16(a, b, c, 0, 0, 0)

__device__ __forceinline__ unsigned short f2bf(float f) {   // RNE f32->bf16
    unsigned u = __float_as_uint(f);
    return (unsigned short)((u + 0x7FFFu + ((u >> 16) & 1u)) >> 16);
}
__device__ __forceinline__ bf16x8 pack8(float4 a, float4 b) {
    bf16x8 r;
    r[0] = (short)f2bf(a.x); r[1] = (short)f2bf(a.y);
    r[2] = (short)f2bf(a.z); r[3] = (short)f2bf(a.w);
    r[4] = (short)f2bf(b.x); r[5] = (short)f2bf(b.y);
    r[6] = (short)f2bf(b.z); r[7] = (short)f2bf(b.w);
    return r;
}
__device__ __forceinline__ float wave_sum(float v) {
#pragma unroll
    for (int s = 32; s >= 1; s >>= 1) v += __shfl_xor(v, s, 64);
    return v;
}

// ---------------- K0: q0 = LN(symbol_queries[pos]) ----------------
__global__ void k_q0(const float* __restrict__ sq, const float* __restrict__ qn_w,
                     const float* __restrict__ qn_b, const int* __restrict__ pos,
                     float* __restrict__ ws) {
    const int t = threadIdx.x;              // 256 threads
    const float4 x = ((const float4*)(sq + (size_t)pos[0] * DD))[t];
    float s  = x.x + x.y + x.z + x.w;
    float s2 = x.x * x.x + x.y * x.y + x.z * x.z + x.w * x.w;
    __shared__ float rs[4], rs2[4];
    s = wave_sum(s); s2 = wave_sum(s2);
    const int w = t >> 6, lane = t & 63;
    if (lane == 0) { rs[w] = s; rs2[w] = s2; }
    __syncthreads();
    s  = rs[0] + rs[1] + rs[2] + rs[3];
    s2 = rs2[0] + rs2[1] + rs2[2] + rs2[3];
    const float mu  = s * (1.0f / DD);
    const float var = s2 * (1.0f / DD) - mu * mu;
    const float rstd = rsqrtf(var + 1e-5f);
    const float4 w4 = ((const float4*)qn_w)[t];
    const float4 b4 = ((const float4*)qn_b)[t];
    float4 o;
    o.x = (x.x - mu) * rstd * w4.x + b4.x;
    o.y = (x.y - mu) * rstd * w4.y + b4.y;
    o.z = (x.z - mu) * rstd * w4.z + b4.z;
    o.w = (x.w - mu) * rstd * w4.w + b4.w;
    ((float4*)(ws + WS_Q0))[t] = o;
}

// ---------------- K1: q = Wq @ q0 + bq  (wave per output) ----------------
__global__ void k_q(const float* __restrict__ ipw, const float* __restrict__ ipb,
                    float* __restrict__ ws) {
    const int w = threadIdx.x >> 6, lane = threadIdx.x & 63;
    const int d = blockIdx.x * 4 + w;
    const float* row = ipw + (size_t)d * DD;
    const float* q0 = ws + WS_Q0;
    float acc = 0.f;
#pragma unroll
    for (int it = 0; it < 4; ++it) {
        float4 a = ((const float4*)row)[lane + 64 * it];
        float4 b = ((const float4*)q0)[lane + 64 * it];
        acc += a.x * b.x + a.y * b.y + a.z * b.z + a.w * b.w;
    }
    acc = wave_sum(acc);
    if (lane == 0) (ws + WS_Q)[d] = acc + ipb[d];
}

// ---------------- K2: r_s[h,e] = scale * sum_j q[h,j] Wk[h*64+j, e] --------
__global__ void k_r(const float* __restrict__ ipw, const float* __restrict__ ipb,
                    float* __restrict__ ws) {
    const int h = blockIdx.x >> 2, qa = blockIdx.x & 3;
    const int t = threadIdx.x;
    const int e = qa * 256 + t;
    const float* q = ws + WS_Q;
    const float* wk = ipw + (size_t)(DD + h * DHH) * DD;
    float acc = 0.f;
#pragma unroll 8
    for (int j = 0; j < DHH; ++j)
        acc += q[h * DHH + j] * wk[(size_t)j * DD + e];
    (ws + WS_R)[h * DD + e] = acc * 0.125f;
    if (qa == 0 && t < 64) {
        float p = q[h * DHH + t] * ipb[DD + h * DHH + t];
        p = wave_sum(p);
        if (t == 0) (ws + WS_C)[h] = p * 0.125f;
    }
}

// ---------------- fused MFMA, software-pipelined --------------
// block = (b, 128-row chunk), 4 waves; 8 tiles of 16 rows, LDS double-buffered.
// Per iter: scores(tt) | BAR | pack+write t(tt+1), issue loads t(tt+2) |
//           finish(tt) | PV(tt) | BAR.  Loads stay in flight across a full
//           compute phase (T14 issue-early/write-late).
// PV keeps mfma 16x16x32 with A zeroed for k>=16 lanes (g>=2): B garbage * 0.
// Staging map: row = wv*4+(lane&3), e = (lane>>2)*4 + 64j -> coalesced global
// float4 loads, 4-way (minimal) LDS b64 write conflict.
__global__ __launch_bounds__(256, 2)
void k_fused(const float* __restrict__ gr, const float* __restrict__ ws,
             float* __restrict__ attn_e, float* __restrict__ part,
             float* __restrict__ ssum) {
    extern __shared__ char smem[];
    const int b  = blockIdx.x >> 4;
    const int ck = blockIdx.x & 15;
    const int l0 = ck * CH;
    const int t  = threadIdx.x;
    const int wv = t >> 6, lane = t & 63;
    const int c16 = lane & 15, g = lane >> 4;
    const int estrip = wv * 256;            // this wave's e-strip

    // ---- prologue: pack r into B-frags (8 k-steps x 32 e), bias ----
    bf16x8 rpk[8];
#pragma unroll
    for (int ks = 0; ks < 8; ++ks) {
        const float* rp = ws + WS_R + (size_t)c16 * DD + estrip + ks * 32 + g * 8;
        rpk[ks] = pack8(*(const float4*)rp, *(const float4*)(rp + 4));
    }
    const float myc = (ws + WS_C)[c16];

    f32x4 pv[16];
#pragma unroll
    for (int i = 0; i < 16; ++i) pv[i] = (f32x4){0.f, 0.f, 0.f, 0.f};
    float s_acc = 0.f;

    // ---- staging geometry ----
    const int srow = wv * 4 + (lane & 3);          // row within 16-row tile
    const int scol = (lane >> 2) * 4;              // e base; e = scol + 64*j
    const float* gbase = gr + ((size_t)(b * LL + l0) + srow) * DD + scol;
    // LDS write byte (within tile buf): j*2048 + (lane>>4)*512 + wv*128
    //                                   + (lane&3)*32 + ((lane>>2)&3)*8
    const int wr_base = (lane >> 4) * 512 + wv * 128 + (lane & 3) * 32 +
                        ((lane >> 2) & 3) * 8;

    float4 raw[16];
    // tile 0: load + pack + write buf0
#pragma unroll
    for (int j = 0; j < 16; ++j) raw[j] = *(const float4*)(gbase + 64 * j);
#pragma unroll
    for (int j = 0; j < 16; ++j) {
        u16x4 p = {f2bf(raw[j].x), f2bf(raw[j].y), f2bf(raw[j].z), f2bf(raw[j].w)};
        *(u16x4*)(smem + wr_base + j * 2048) = p;
    }
    // issue tile 1 loads
#pragma unroll
    for (int j = 0; j < 16; ++j)
        raw[j] = *(const float4*)(gbase + 16 * DD + 64 * j);
    __syncthreads();

#pragma unroll 1
    for (int tt = 0; tt < NT; ++tt) {
        const char* rb = smem + (tt & 1) * 32768;
        // ---- scores(tt): 8 k-steps over this wave's e-strip ----
        f32x4 sa = {0.f, 0.f, 0.f, 0.f};
#pragma unroll
        for (int ks = 0; ks < 8; ++ks) {
            const int e16 = wv * 16 + ks * 2 + (g >> 1);
            const int byt = (e16 * 4 + (c16 >> 2)) * 128 + (c16 & 3) * 32 + (g & 1) * 16;
            bf16x8 a = *(const bf16x8*)(rb + byt);
            sa = MFMA(a, rpk[ks], sa);
        }
        *(f32x4*)(smem + RED_OFF + (wv * 64 + lane) * 16) = sa;
        __syncthreads();                    // red visible; buf[(tt+1)&1] free
        // ---- stage tile tt+1 (pack from in-flight regs), issue tt+2 ----
        if (tt < NT - 1) {
            char* wb = smem + ((tt + 1) & 1) * 32768;
#pragma unroll
            for (int j = 0; j < 16; ++j) {
                u16x4 p = {f2bf(raw[j].x), f2bf(raw[j].y), f2bf(raw[j].z), f2bf(raw[j].w)};
                *(u16x4*)(wb + wr_base + j * 2048) = p;
            }
            if (tt < NT - 2) {
                const float* gs = gbase + (size_t)(tt + 2) * 16 * DD;
#pragma unroll
                for (int j = 0; j < 16; ++j)
                    raw[j] = *(const float4*)(gs + 64 * j);
            }
        }
        // ---- finish(tt): sum 4 wave-partials + bias, exp ----
        f32x4 tot = {myc, myc, myc, myc};
#pragma unroll
        for (int w2 = 0; w2 < 4; ++w2)
            tot += *(const f32x4*)(smem + RED_OFF + (w2 * 64 + lane) * 16);
        f32x4 ex;                           // no max-shift: |score| ~ O(1)
        ex[0] = __expf(tot[0]); ex[1] = __expf(tot[1]);
        ex[2] = __expf(tot[2]); ex[3] = __expf(tot[3]);
        u16x4 wp = {f2bf(ex[0]), f2bf(ex[1]), f2bf(ex[2]), f2bf(ex[3])};
        *(u16x4*)(smem + WT_OFF + wv * 512 + c16 * 32 + g * 8) = wp;
        if (wv == 0) {                      // attn (unnormalized exp) store
            float* ap = attn_e + ((size_t)b * HH + c16) * LL + l0 + tt * 16 + g * 4;
            *(float4*)ap = make_float4(ex[0], ex[1], ex[2], ex[3]);
        }
        s_acc += ex[0] + ex[1] + ex[2] + ex[3];
        // ---- PV(tt): A = wt (zero for k>=16 lanes), B = tr-reads of G ----
        bf16x8 afrag;
        if (g < 2) {
            afrag = *(const bf16x8*)(smem + WT_OFF + wv * 512 + c16 * 32 + g * 16);
        } else {
            afrag = (bf16x8){0, 0, 0, 0, 0, 0, 0, 0};
        }
#pragma unroll
        for (int grp = 0; grp < 4; ++grp) {
            u32x2 q[8];
#pragma unroll
            for (int n2 = 0; n2 < 4; ++n2) {
                const int est = wv * 16 + grp * 4 + n2;
                const unsigned ta = (unsigned)((tt & 1) * 32768 + est * 512 +
                                               (g & 1) * 256 + c16 * 8);
                asm volatile("ds_read_b64_tr_b16 %0, %1"
                             : "=v"(q[n2 * 2]) : "v"(ta));
                asm volatile("ds_read_b64_tr_b16 %0, %1 offset:128"
                             : "=v"(q[n2 * 2 + 1]) : "v"(ta));
            }
            asm volatile("s_waitcnt lgkmcnt(0)" ::: "memory");
            __builtin_amdgcn_sched_barrier(0);
#pragma unroll
            for (int n2 = 0; n2 < 4; ++n2) {
                union { unsigned u[4]; bf16x8 v; } bb;
                bb.u[0] = q[n2 * 2][0];     bb.u[1] = q[n2 * 2][1];
                bb.u[2] = q[n2 * 2 + 1][0]; bb.u[3] = q[n2 * 2 + 1][1];
                pv[grp * 4 + n2] = MFMA(afrag, bb.v, pv[grp * 4 + n2]);
            }
        }
        __syncthreads();                    // stage(tt+1) visible; red free
    }
    // ---- epilogue: ssum + partials ----
    float sv = s_acc;
    sv += __shfl_xor(sv, 16, 64);
    sv += __shfl_xor(sv, 32, 64);
    if (wv == 0 && lane < 16)
        ssum[((size_t)b * NCK + ck) * HH + c16] = sv;
    float* pp = part + ((size_t)b * NCK + ck) * (HH * DD);
#pragma unroll
    for (int nt = 0; nt < 16; ++nt) {
#pragma unroll
        for (int r2 = 0; r2 < 4; ++r2)
            pp[(size_t)(g * 4 + r2) * DD + estrip + nt * 16 + c16] = pv[nt][r2];
    }
}

// ---------------- combine + attn-normalize + Wv: ctx[b, h*64+j] ------------
__global__ void k_ctx(const float* __restrict__ ipw, const float* __restrict__ ipb,
                      const float* __restrict__ part, const float* __restrict__ ssum,
                      float* __restrict__ attn_e, float* __restrict__ ctx) {
    const int bh = blockIdx.x, b = bh >> 4, h = bh & 15;   // 512 blocks
    const int t = threadIdx.x, w = t >> 6, lane = t & 63;  // 256
    float S = 0.f;
#pragma unroll
    for (int c = 0; c < NCK; ++c) S += ssum[((size_t)b * NCK + c) * HH + h];
    const float inv = 1.0f / S;
    float4* ar = (float4*)(attn_e + (size_t)bh * LL);
#pragma unroll
    for (int i = 0; i < 2; ++i) {
        float4 v = ar[t + 256 * i];
        v.x *= inv; v.y *= inv; v.z *= inv; v.w *= inv;
        ar[t + 256 * i] = v;
    }
    __shared__ float Xl[DD];
    float4 x = {0.f, 0.f, 0.f, 0.f};
#pragma unroll
    for (int c = 0; c < NCK; ++c) {
        float4 p = ((const float4*)(part + ((size_t)b * NCK + c) * (HH * DD) + h * DD))[t];
        x.x += p.x; x.y += p.y; x.z += p.z; x.w += p.w;
    }
    float4 xs = {x.x * inv, x.y * inv, x.z * inv, x.w * inv};
    ((float4*)Xl)[t] = xs;
    __syncthreads();
    for (int jj = 0; jj < 16; ++jj) {
        const int j = w * 16 + jj;
        const float* row = ipw + (size_t)(2 * DD + h * DHH + j) * DD;
        float acc = 0.f;
#pragma unroll
        for (int it = 0; it < 4; ++it) {
            float4 a = ((const float4*)row)[lane + 64 * it];
            float4 p = ((const float4*)Xl)[lane + 64 * it];
            acc += a.x * p.x + a.y * p.y + a.z * p.z + a.w * p.w;
        }
        acc = wave_sum(acc);
        if (lane == 0) ctx[(size_t)b * DD + h * DHH + j] = acc + ipb[2 * DD + h * DHH + j];
    }
}

// ---------------- y[b, d'] = out_w[d',:]·ctx[b,:] + out_b ----------------
__global__ void k_y(const float* __restrict__ ow, const float* __restrict__ ob,
                    const float* __restrict__ ctx, float* __restrict__ y) {
    const int blk = blockIdx.x, b = blk >> 4, ch = blk & 15;  // 512 blocks
    const int t = threadIdx.x, w = t >> 6, lane = t & 63;     // 256
    __shared__ float Xl[DD];
    ((float4*)Xl)[t] = ((const float4*)(ctx + (size_t)b * DD))[t];
    __syncthreads();
    for (int jj = 0; jj < 16; ++jj) {
        const int d = ch * 64 + w * 16 + jj;
        const float* row = ow + (size_t)d * DD;
        float acc = 0.f;
#pragma unroll
        for (int it = 0; it < 4; ++it) {
            float4 a = ((const float4*)row)[lane + 64 * it];
            float4 p = ((const float4*)Xl)[lane + 64 * it];
            acc += a.x * p.x + a.y * p.y + a.z * p.z + a.w * p.w;
        }
        acc = wave_sum(acc);
        if (lane == 0) y[(size_t)b * DD + d] = acc + ob[d];
    }
}

// ---------------- final LN -> pooled output ----------------
__global__ void k_lnout(const float* __restrict__ y, const float* __restrict__ on_w,
                        const float* __restrict__ on_b, float* __restrict__ outp) {
    const int b = blockIdx.x, t = threadIdx.x;   // 32 blocks, 256 threads
    const float4 x = ((const float4*)(y + (size_t)b * DD))[t];
    float s  = x.x + x.y + x.z + x.w;
    float s2 = x.x * x.x + x.y * x.y + x.z * x.z + x.w * x.w;
    __shared__ float rs[4], rs2[4];
    s = wave_sum(s); s2 = wave_sum(s2);
    const int w = t >> 6, lane = t & 63;
    if (lane == 0) { rs[w] = s; rs2[w] = s2; }
    __syncthreads();
    s  = rs[0] + rs[1] + rs[2] + rs[3];
    s2 = rs2[0] + rs2[1] + rs2[2] + rs2[3];
    const float mu  = s * (1.0f / DD);
    const float var = s2 * (1.0f / DD) - mu * mu;
    const float rstd = rsqrtf(var + 1e-5f);
    const float4 w4 = ((const float4*)on_w)[t];
    const float4 b4 = ((const float4*)on_b)[t];
    float4 o;
    o.x = (x.x - mu) * rstd * w4.x + b4.x;
    o.y = (x.y - mu) * rstd * w4.y + b4.y;
    o.z = (x.z - mu) * rstd * w4.z + b4.z;
    o.w = (x.w - mu) * rstd * w4.w + b4.w;
    ((float4*)(outp + (size_t)b * DD))[t] = o;
}

extern "C" void kernel_launch(void* const* d_in, const int* in_sizes, int n_in,
                              void* d_out, int out_size, void* d_ws, size_t ws_size,
                              hipStream_t stream) {
    const float* gr   = (const float*)d_in[0];
    const float* sq   = (const float*)d_in[1];
    const float* qn_w = (const float*)d_in[2];
    const float* qn_b = (const float*)d_in[3];
    const float* ipw  = (const float*)d_in[4];
    const float* ipb  = (const float*)d_in[5];
    const float* ow   = (const float*)d_in[6];
    const float* ob   = (const float*)d_in[7];
    const float* on_w = (const float*)d_in[8];
    const float* on_b = (const float*)d_in[9];
    const int*   pos  = (const int*)d_in[10];

    float* out  = (float*)d_out;
    float* attn = out + BB * DD;           // output 1; holds exp(score) until k_ctx norms
    float* ws   = (float*)d_ws;

    hipFuncSetAttribute((const void*)k_fused,
                        hipFuncAttributeMaxDynamicSharedMemorySize, SMEM_BYTES);

    k_q0<<<1, 256, 0, stream>>>(sq, qn_w, qn_b, pos, ws);
    k_q<<<256, 256, 0, stream>>>(ipw, ipb, ws);
    k_r<<<64, 256, 0, stream>>>(ipw, ipb, ws);
    k_fused<<<BB * NCK, 256, SMEM_BYTES, stream>>>(gr, ws, attn,
                                                   ws + WS_PART, ws + WS_SSUM);
    k_ctx<<<BB * HH, 256, 0, stream>>>(ipw, ipb, ws + WS_PART, ws + WS_SSUM,
                                       attn, ws + WS_CTX);
    k_y<<<BB * 16, 256, 0, stream>>>(ow, ob, ws + WS_CTX, ws + WS_Y);
    k_lnout<<<BB, 256, 0, stream>>>(ws + WS_Y, on_w, on_b, out);
}

// Round 10
// 102.914 us; speedup vs baseline: 4.5248x; 1.1132x over previous
//
#include <hip/hip_runtime.h>
#include <math.h>

#define BB 32
#define LL 2048
#define DD 1024
#define HH 16
#define DHH 64
#define NCK 16         // chunks per batch
#define CH  128        // rows per chunk
#define NT  8          // 16-row tiles per chunk

// ---- ws layout (float offsets) ----
#define WS_Q     1024       // 1024
#define WS_R     2048       // 16*1024
#define WS_C     18432      // 64 (16 used)
#define WS_CTX   19008      // 32768
#define WS_Y     51776      // 32768
#define WS_SSUM  84544      // 32*16*16 = 8192
#define WS_PART  92736      // 32*16*16*1024 bf16 = 16 MB

// ---- k_fused dynamic LDS layout (bytes) ----
// G tile buffers: 2 x (16 rows x 1024 e bf16, [4 l][16 e]-subtiled) = 2x32768
//   byte(l,e) = (e>>4)*512 + (l>>2)*128 + (l&3)*32 + (e&15)*2
#define RED_OFF  65536      // 4 waves x 64 lanes x 4 f32 = 4096
#define WT_OFF   69632      // 4 waves x 16 h x 16 l bf16 = 2048
#define SMEM_BYTES 71680

typedef __attribute__((ext_vector_type(8))) short    bf16x8;
typedef __attribute__((ext_vector_type(4))) float    f32x4;
typedef __attribute__((ext_vector_type(2))) unsigned u32x2;
typedef __attribute__((ext_vector_type(4))) unsigned short u16x4;

#define MFMA(a, b, c) __builtin_amdgcn_mfma_f32_16x16x32_bf16(a, b, c, 0, 0, 0)

__device__ __forceinline__ unsigned short f2bf(float f) {   // RNE f32->bf16
    unsigned u = __float_as_uint(f);
    return (unsigned short)((u + 0x7FFFu + ((u >> 16) & 1u)) >> 16);
}
__device__ __forceinline__ float bf2f(unsigned short u) {
    return __uint_as_float((unsigned)u << 16);
}
__device__ __forceinline__ float wave_sum(float v) {
#pragma unroll
    for (int s = 32; s >= 1; s >>= 1) v += __shfl_xor(v, s, 64);
    return v;
}

// ---------------- K1: q = Wq @ LN(sq[pos]) + bq  (LN fused, wave/output) ----
__global__ void k_q(const float* __restrict__ sq, const float* __restrict__ qn_w,
                    const float* __restrict__ qn_b, const int* __restrict__ pos,
                    const float* __restrict__ ipw, const float* __restrict__ ipb,
                    float* __restrict__ ws) {
    const int t = threadIdx.x;              // 256 threads
    const int w = t >> 6, lane = t & 63;
    __shared__ float q0s[DD];
    __shared__ float rs[4], rs2[4];
    {   // redundant per-block LN of the single query row (4 KB, L2-hot)
        const float4 x = ((const float4*)(sq + (size_t)pos[0] * DD))[t];
        float s  = x.x + x.y + x.z + x.w;
        float s2 = x.x * x.x + x.y * x.y + x.z * x.z + x.w * x.w;
        s = wave_sum(s); s2 = wave_sum(s2);
        if (lane == 0) { rs[w] = s; rs2[w] = s2; }
        __syncthreads();
        s  = rs[0] + rs[1] + rs[2] + rs[3];
        s2 = rs2[0] + rs2[1] + rs2[2] + rs2[3];
        const float mu  = s * (1.0f / DD);
        const float var = s2 * (1.0f / DD) - mu * mu;
        const float rstd = rsqrtf(var + 1e-5f);
        const float4 w4 = ((const float4*)qn_w)[t];
        const float4 b4 = ((const float4*)qn_b)[t];
        float4 o;
        o.x = (x.x - mu) * rstd * w4.x + b4.x;
        o.y = (x.y - mu) * rstd * w4.y + b4.y;
        o.z = (x.z - mu) * rstd * w4.z + b4.z;
        o.w = (x.w - mu) * rstd * w4.w + b4.w;
        ((float4*)q0s)[t] = o;
    }
    __syncthreads();
    const int d = blockIdx.x * 4 + w;       // 256 blocks * 4 waves = 1024 outputs
    const float* row = ipw + (size_t)d * DD;
    float acc = 0.f;
#pragma unroll
    for (int it = 0; it < 4; ++it) {
        float4 a = ((const float4*)row)[lane + 64 * it];
        float4 b = ((const float4*)q0s)[lane + 64 * it];
        acc += a.x * b.x + a.y * b.y + a.z * b.z + a.w * b.w;
    }
    acc = wave_sum(acc);
    if (lane == 0) (ws + WS_Q)[d] = acc + ipb[d];
}

// ---------------- K2: r_s[h,e] = scale * sum_j q[h,j] Wk[h*64+j, e] --------
__global__ void k_r(const float* __restrict__ ipw, const float* __restrict__ ipb,
                    float* __restrict__ ws) {
    const int h = blockIdx.x >> 2, qa = blockIdx.x & 3;
    const int t = threadIdx.x;
    const int e = qa * 256 + t;
    const float* q = ws + WS_Q;
    const float* wk = ipw + (size_t)(DD + h * DHH) * DD;
    float acc = 0.f;
#pragma unroll 8
    for (int j = 0; j < DHH; ++j)
        acc += q[h * DHH + j] * wk[(size_t)j * DD + e];
    (ws + WS_R)[h * DD + e] = acc * 0.125f;
    if (qa == 0 && t < 64) {
        float p = q[h * DHH + t] * ipb[DD + h * DHH + t];
        p = wave_sum(p);
        if (t == 0) (ws + WS_C)[h] = p * 0.125f;
    }
}

// ---------------- fused MFMA, software-pipelined --------------
// block = (b, 128-row chunk), 4 waves; 8 tiles of 16 rows, LDS double-buffered.
// Per iter: scores(tt) | BAR | pack+write t(tt+1), issue loads t(tt+2) |
//           finish(tt) | PV(tt) | BAR.
// Staging map (R10): srow = wv*4 + ((lane>>2)&3), e = (lane>>4)*16+(lane&3)*4
//   + 64j  ->  write byte%128 = (lane&15)*8: conflict-free b64 writes
//   (R9's map was 4-way).  Read-side layout formula unchanged.
// PV keeps mfma 16x16x32 with A zeroed for k>=16 lanes (g>=2).
__global__ __launch_bounds__(256, 2)
void k_fused(const float* __restrict__ gr, const float* __restrict__ ws,
             float* __restrict__ attn_e, unsigned short* __restrict__ part,
             float* __restrict__ ssum) {
    extern __shared__ char smem[];
    const int b  = blockIdx.x >> 4;
    const int ck = blockIdx.x & 15;
    const int l0 = ck * CH;
    const int t  = threadIdx.x;
    const int wv = t >> 6, lane = t & 63;
    const int c16 = lane & 15, g = lane >> 4;
    const int estrip = wv * 256;            // this wave's e-strip

    // ---- prologue: pack r into B-frags (8 k-steps x 32 e), bias ----
    bf16x8 rpk[8];
#pragma unroll
    for (int ks = 0; ks < 8; ++ks) {
        const float* rp = ws + WS_R + (size_t)c16 * DD + estrip + ks * 32 + g * 8;
        float4 f0 = *(const float4*)rp, f1 = *(const float4*)(rp + 4);
        bf16x8 r;
        r[0] = (short)f2bf(f0.x); r[1] = (short)f2bf(f0.y);
        r[2] = (short)f2bf(f0.z); r[3] = (short)f2bf(f0.w);
        r[4] = (short)f2bf(f1.x); r[5] = (short)f2bf(f1.y);
        r[6] = (short)f2bf(f1.z); r[7] = (short)f2bf(f1.w);
        rpk[ks] = r;
    }
    const float myc = (ws + WS_C)[c16];

    f32x4 pv[16];
#pragma unroll
    for (int i = 0; i < 16; ++i) pv[i] = (f32x4){0.f, 0.f, 0.f, 0.f};
    float s_acc = 0.f;

    // ---- staging geometry (conflict-free map) ----
    const int srow = wv * 4 + ((lane >> 2) & 3);   // row within 16-row tile
    const int scol = (lane >> 4) * 16 + (lane & 3) * 4;  // e base; e = scol+64j
    const float* gbase = gr + ((size_t)(b * LL + l0) + srow) * DD + scol;
    // write byte (j=0): e16*512 + (srow>>2)*128 + (srow&3)*32 + (e&15)*2
    const int wr_base = (lane >> 4) * 512 + wv * 128 + ((lane >> 2) & 3) * 32 +
                        (lane & 3) * 8;

    float4 raw[16];
    // tile 0: load + pack + write buf0
#pragma unroll
    for (int j = 0; j < 16; ++j) raw[j] = *(const float4*)(gbase + 64 * j);
#pragma unroll
    for (int j = 0; j < 16; ++j) {
        u16x4 p = {f2bf(raw[j].x), f2bf(raw[j].y), f2bf(raw[j].z), f2bf(raw[j].w)};
        *(u16x4*)(smem + wr_base + j * 2048) = p;
    }
    // issue tile 1 loads
#pragma unroll
    for (int j = 0; j < 16; ++j)
        raw[j] = *(const float4*)(gbase + 16 * DD + 64 * j);
    __syncthreads();

#pragma unroll 1
    for (int tt = 0; tt < NT; ++tt) {
        const char* rb = smem + (tt & 1) * 32768;
        // ---- scores(tt): 8 k-steps over this wave's e-strip ----
        f32x4 sa = {0.f, 0.f, 0.f, 0.f};
#pragma unroll
        for (int ks = 0; ks < 8; ++ks) {
            const int e16 = wv * 16 + ks * 2 + (g >> 1);
            const int byt = (e16 * 4 + (c16 >> 2)) * 128 + (c16 & 3) * 32 + (g & 1) * 16;
            bf16x8 a = *(const bf16x8*)(rb + byt);
            sa = MFMA(a, rpk[ks], sa);
        }
        *(f32x4*)(smem + RED_OFF + (wv * 64 + lane) * 16) = sa;
        __syncthreads();                    // red visible; buf[(tt+1)&1] free
        // ---- stage tile tt+1 (pack from in-flight regs), issue tt+2 ----
        if (tt < NT - 1) {
            char* wb = smem + ((tt + 1) & 1) * 32768;
#pragma unroll
            for (int j = 0; j < 16; ++j) {
                u16x4 p = {f2bf(raw[j].x), f2bf(raw[j].y), f2bf(raw[j].z), f2bf(raw[j].w)};
                *(u16x4*)(wb + wr_base + j * 2048) = p;
            }
            if (tt < NT - 2) {
                const float* gs = gbase + (size_t)(tt + 2) * 16 * DD;
#pragma unroll
                for (int j = 0; j < 16; ++j)
                    raw[j] = *(const float4*)(gs + 64 * j);
            }
        }
        // ---- finish(tt): sum 4 wave-partials + bias, exp ----
        f32x4 tot = {myc, myc, myc, myc};
#pragma unroll
        for (int w2 = 0; w2 < 4; ++w2)
            tot += *(const f32x4*)(smem + RED_OFF + (w2 * 64 + lane) * 16);
        f32x4 ex;                           // no max-shift: |score| ~ O(1)
        ex[0] = __expf(tot[0]); ex[1] = __expf(tot[1]);
        ex[2] = __expf(tot[2]); ex[3] = __expf(tot[3]);
        u16x4 wp = {f2bf(ex[0]), f2bf(ex[1]), f2bf(ex[2]), f2bf(ex[3])};
        *(u16x4*)(smem + WT_OFF + wv * 512 + c16 * 32 + g * 8) = wp;
        if (wv == 0) {                      // attn (unnormalized exp) store
            float* ap = attn_e + ((size_t)b * HH + c16) * LL + l0 + tt * 16 + g * 4;
            *(float4*)ap = make_float4(ex[0], ex[1], ex[2], ex[3]);
        }
        s_acc += ex[0] + ex[1] + ex[2] + ex[3];
        // ---- PV(tt): A = wt (zero for k>=16 lanes), B = tr-reads of G ----
        bf16x8 afrag;
        if (g < 2) {
            afrag = *(const bf16x8*)(smem + WT_OFF + wv * 512 + c16 * 32 + g * 16);
        } else {
            afrag = (bf16x8){0, 0, 0, 0, 0, 0, 0, 0};
        }
#pragma unroll
        for (int grp = 0; grp < 4; ++grp) {
            u32x2 q[8];
#pragma unroll
            for (int n2 = 0; n2 < 4; ++n2) {
                const int est = wv * 16 + grp * 4 + n2;
                const unsigned ta = (unsigned)((tt & 1) * 32768 + est * 512 +
                                               (g & 1) * 256 + c16 * 8);
                asm volatile("ds_read_b64_tr_b16 %0, %1"
                             : "=v"(q[n2 * 2]) : "v"(ta));
                asm volatile("ds_read_b64_tr_b16 %0, %1 offset:128"
                             : "=v"(q[n2 * 2 + 1]) : "v"(ta));
            }
            asm volatile("s_waitcnt lgkmcnt(0)" ::: "memory");
            __builtin_amdgcn_sched_barrier(0);
#pragma unroll
            for (int n2 = 0; n2 < 4; ++n2) {
                union { unsigned u[4]; bf16x8 v; } bb;
                bb.u[0] = q[n2 * 2][0];     bb.u[1] = q[n2 * 2][1];
                bb.u[2] = q[n2 * 2 + 1][0]; bb.u[3] = q[n2 * 2 + 1][1];
                pv[grp * 4 + n2] = MFMA(afrag, bb.v, pv[grp * 4 + n2]);
            }
        }
        __syncthreads();                    // stage(tt+1) visible; red free
    }
    // ---- epilogue: ssum + partials (bf16) ----
    float sv = s_acc;
    sv += __shfl_xor(sv, 16, 64);
    sv += __shfl_xor(sv, 32, 64);
    if (wv == 0 && lane < 16)
        ssum[((size_t)b * NCK + ck) * HH + c16] = sv;
    unsigned short* pp = part + ((size_t)b * NCK + ck) * (HH * DD);
#pragma unroll
    for (int nt = 0; nt < 16; ++nt) {
#pragma unroll
        for (int r2 = 0; r2 < 4; ++r2)
            pp[(size_t)(g * 4 + r2) * DD + estrip + nt * 16 + c16] = f2bf(pv[nt][r2]);
    }
}

// ---------------- combine + attn-normalize + Wv: ctx[b, h*64+j] ------------
__global__ void k_ctx(const float* __restrict__ ipw, const float* __restrict__ ipb,
                      const unsigned short* __restrict__ part,
                      const float* __restrict__ ssum,
                      float* __restrict__ attn_e, float* __restrict__ ctx) {
    const int bh = blockIdx.x, b = bh >> 4, h = bh & 15;   // 512 blocks
    const int t = threadIdx.x, w = t >> 6, lane = t & 63;  // 256
    float S = 0.f;
#pragma unroll
    for (int c = 0; c < NCK; ++c) S += ssum[((size_t)b * NCK + c) * HH + h];
    const float inv = 1.0f / S;
    float4* ar = (float4*)(attn_e + (size_t)bh * LL);
#pragma unroll
    for (int i = 0; i < 2; ++i) {
        float4 v = ar[t + 256 * i];
        v.x *= inv; v.y *= inv; v.z *= inv; v.w *= inv;
        ar[t + 256 * i] = v;
    }
    __shared__ float Xl[DD];
    float4 x = {0.f, 0.f, 0.f, 0.f};
#pragma unroll
    for (int c = 0; c < NCK; ++c) {
        u16x4 p = *(const u16x4*)(part + ((size_t)b * NCK + c) * (HH * DD) +
                                  (size_t)h * DD + t * 4);
        x.x += bf2f(p[0]); x.y += bf2f(p[1]);
        x.z += bf2f(p[2]); x.w += bf2f(p[3]);
    }
    float4 xs = {x.x * inv, x.y * inv, x.z * inv, x.w * inv};
    ((float4*)Xl)[t] = xs;
    __syncthreads();
    for (int jj = 0; jj < 16; ++jj) {
        const int j = w * 16 + jj;
        const float* row = ipw + (size_t)(2 * DD + h * DHH + j) * DD;
        float acc = 0.f;
#pragma unroll
        for (int it = 0; it < 4; ++it) {
            float4 a = ((const float4*)row)[lane + 64 * it];
            float4 p = ((const float4*)Xl)[lane + 64 * it];
            acc += a.x * p.x + a.y * p.y + a.z * p.z + a.w * p.w;
        }
        acc = wave_sum(acc);
        if (lane == 0) ctx[(size_t)b * DD + h * DHH + j] = acc + ipb[2 * DD + h * DHH + j];
    }
}

// ---------------- y[b, d'] = out_w[d',:]·ctx[b,:] + out_b ----------------
__global__ void k_y(const float* __restrict__ ow, const float* __restrict__ ob,
                    const float* __restrict__ ctx, float* __restrict__ y) {
    const int blk = blockIdx.x, b = blk >> 4, ch = blk & 15;  // 512 blocks
    const int t = threadIdx.x, w = t >> 6, lane = t & 63;     // 256
    __shared__ float Xl[DD];
    ((float4*)Xl)[t] = ((const float4*)(ctx + (size_t)b * DD))[t];
    __syncthreads();
    for (int jj = 0; jj < 16; ++jj) {
        const int d = ch * 64 + w * 16 + jj;
        const float* row = ow + (size_t)d * DD;
        float acc = 0.f;
#pragma unroll
        for (int it = 0; it < 4; ++it) {
            float4 a = ((const float4*)row)[lane + 64 * it];
            float4 p = ((const float4*)Xl)[lane + 64 * it];
            acc += a.x * p.x + a.y * p.y + a.z * p.z + a.w * p.w;
        }
        acc = wave_sum(acc);
        if (lane == 0) y[(size_t)b * DD + d] = acc + ob[d];
    }
}

// ---------------- final LN -> pooled output ----------------
__global__ void k_lnout(const float* __restrict__ y, const float* __restrict__ on_w,
                        const float* __restrict__ on_b, float* __restrict__ outp) {
    const int b = blockIdx.x, t = threadIdx.x;   // 32 blocks, 256 threads
    const float4 x = ((const float4*)(y + (size_t)b * DD))[t];
    float s  = x.x + x.y + x.z + x.w;
    float s2 = x.x * x.x + x.y * x.y + x.z * x.z + x.w * x.w;
    __shared__ float rs[4], rs2[4];
    s = wave_sum(s); s2 = wave_sum(s2);
    const int w = t >> 6, lane = t & 63;
    if (lane == 0) { rs[w] = s; rs2[w] = s2; }
    __syncthreads();
    s  = rs[0] + rs[1] + rs[2] + rs[3];
    s2 = rs2[0] + rs2[1] + rs2[2] + rs2[3];
    const float mu  = s * (1.0f / DD);
    const float var = s2 * (1.0f / DD) - mu * mu;
    const float rstd = rsqrtf(var + 1e-5f);
    const float4 w4 = ((const float4*)on_w)[t];
    const float4 b4 = ((const float4*)on_b)[t];
    float4 o;
    o.x = (x.x - mu) * rstd * w4.x + b4.x;
    o.y = (x.y - mu) * rstd * w4.y + b4.y;
    o.z = (x.z - mu) * rstd * w4.z + b4.z;
    o.w = (x.w - mu) * rstd * w4.w + b4.w;
    ((float4*)(outp + (size_t)b * DD))[t] = o;
}

extern "C" void kernel_launch(void* const* d_in, const int* in_sizes, int n_in,
                              void* d_out, int out_size, void* d_ws, size_t ws_size,
                              hipStream_t stream) {
    const float* gr   = (const float*)d_in[0];
    const float* sq   = (const float*)d_in[1];
    const float* qn_w = (const float*)d_in[2];
    const float* qn_b = (const float*)d_in[3];
    const float* ipw  = (const float*)d_in[4];
    const float* ipb  = (const float*)d_in[5];
    const float* ow   = (const float*)d_in[6];
    const float* ob   = (const float*)d_in[7];
    const float* on_w = (const float*)d_in[8];
    const float* on_b = (const float*)d_in[9];
    const int*   pos  = (const int*)d_in[10];

    float* out  = (float*)d_out;
    float* attn = out + BB * DD;           // output 1; holds exp(score) until k_ctx norms
    float* ws   = (float*)d_ws;
    unsigned short* part16 = (unsigned short*)(ws + WS_PART);

    hipFuncSetAttribute((const void*)k_fused,
                        hipFuncAttributeMaxDynamicSharedMemorySize, SMEM_BYTES);

    k_q<<<256, 256, 0, stream>>>(sq, qn_w, qn_b, pos, ipw, ipb, ws);
    k_r<<<64, 256, 0, stream>>>(ipw, ipb, ws);
    k_fused<<<BB * NCK, 256, SMEM_BYTES, stream>>>(gr, ws, attn,
                                                   part16, ws + WS_SSUM);
    k_ctx<<<BB * HH, 256, 0, stream>>>(ipw, ipb, part16, ws + WS_SSUM,
                                       attn, ws + WS_CTX);
    k_y<<<BB * 16, 256, 0, stream>>>(ow, ob, ws + WS_CTX, ws + WS_Y);
    k_lnout<<<BB, 256, 0, stream>>>(ws + WS_Y, on_w, on_b, out);
}